// Round 1
// baseline (160033.630 us; speedup 1.0000x reference)
//
#include <hip/hip_runtime.h>
#include <math.h>

// ---------------- problem constants ----------------
#define T_LEN 2048
#define B_SZ  128
#define H_SZ  256
#define NGRP  8      // batch groups (16 batches each)
#define NSLC  32     // gate slices (blocks per group)
#define BPG   16     // batches per group
#define NTH   512    // threads per block
#define WST   260    // padded LDS row stride (floats); 260/4=65 odd -> conflict-free b128
#define GPST  35     // gate-partial stride (floats), breaks 8-way conflicts

// ---------------- ws layout (float/int units) ----------------
#define H1G_OFF 0              // 2 * 128 * 256 floats (ping-pong h1)
#define H2G_OFF 65536          // 2 * 128 * 256 floats (ping-pong h2)
#define BAR_OFF 131072         // 8 groups * 64 ints (arrive@0, epoch@16), abort @ 8*64
#define WS_INTS (131072 + 512 + 1)
// total ws bytes needed: 526,340

// ---------------- LDS layout (float offsets), total 38592 floats = 154368 B ----
// whh0 0, wih1 8320, whh1 16640, h1c 24960, h2c 29056,
// gp0 33152 (64*35), gp1 35392, wfc 37632, wih0 38144, b0 38272, b1 38304, fcp 38336

__device__ __forceinline__ float sigm(float x) { return 1.0f / (1.0f + expf(-x)); }

__global__ void init_ws_kernel(int* ws) {
  for (int i = blockIdx.x * blockDim.x + threadIdx.x; i < WS_INTS;
       i += gridDim.x * blockDim.x)
    ws[i] = 0;
}

__launch_bounds__(NTH)
__global__ void lstm_persist(const float* __restrict__ y,
                             const float* __restrict__ Wih0, const float* __restrict__ Whh0,
                             const float* __restrict__ bih0, const float* __restrict__ bhh0,
                             const float* __restrict__ Wih1, const float* __restrict__ Whh1,
                             const float* __restrict__ bih1, const float* __restrict__ bhh1,
                             const float* __restrict__ Wfc, const float* __restrict__ bfc,
                             float* __restrict__ out, float* wsf) {
  extern __shared__ float sm[];
  float* whh0_s = sm;
  float* wih1_s = sm + 8320;
  float* whh1_s = sm + 16640;
  float* h1c    = sm + 24960;   // [16][256]  h1_{p-1}
  float* h2c    = sm + 29056;   // [16][256]  h2_{p-2}
  float* gp0    = sm + 33152;   // [64][GPST] partial gates L0
  float* gp1    = sm + 35392;   // [64][GPST] partial gates L1
  float* wfc_s  = sm + 37632;   // [2][256]
  float* wih0_s = sm + 38144;   // [32][4]
  float* b0_s   = sm + 38272;   // [32]
  float* b1_s   = sm + 38304;   // [32]
  float* fcp    = sm + 38336;   // [16][2][8]

  const int tid   = threadIdx.x;
  const int group = blockIdx.x & 7;    // consecutive blockIdx -> round-robin XCD: group is XCD-local
  const int slice = blockIdx.x >> 3;   // 0..31

  float* h1g = wsf + H1G_OFF;
  float* h2g = wsf + H2G_OFF;
  int* bar    = (int*)wsf + BAR_OFF;
  int* arrive = bar + group * 64;
  int* epoch  = bar + group * 64 + 16;
  int* abortf = bar + NGRP * 64;

  // ---- stage persistent weight slice into LDS (once) ----
  for (int i = tid; i < 32 * 256; i += NTH) {
    int rl = i >> 8, k = i & 255;                       // rl = gate*8 + hh
    int gr = (rl >> 3) * 256 + slice * 8 + (rl & 7);    // global gate row
    whh0_s[rl * WST + k] = Whh0[gr * 256 + k];
    wih1_s[rl * WST + k] = Wih1[gr * 256 + k];
    whh1_s[rl * WST + k] = Whh1[gr * 256 + k];
  }
  if (tid < 128) {
    int rl = tid >> 2, k = tid & 3;
    int gr = (rl >> 3) * 256 + slice * 8 + (rl & 7);
    wih0_s[tid] = Wih0[gr * 4 + k];
  }
  if (tid < 32) {
    int gr = (tid >> 3) * 256 + slice * 8 + (tid & 7);
    b0_s[tid] = bih0[gr] + bhh0[gr];
    b1_s[tid] = bih1[gr] + bhh1[gr];
  }
  for (int i = tid; i < 512; i += NTH) wfc_s[i] = Wfc[i];
  __syncthreads();

  // dot-phase roles
  const int row = tid & 31;         // local gate row
  const int bq  = (tid >> 5) & 3;   // batch quad
  const int kq  = tid >> 7;         // k chunk (64 wide)

  float c1 = 0.f, c2 = 0.f;         // cell state slices (tid<128 holds c1, 128..255 holds c2)

  // phases: p computes L0(step p), L1(step p-1), FC(step p-2); one group barrier per phase
  for (int p = 0; p <= T_LEN + 1; ++p) {
    const bool doL0 = (p < T_LEN);
    const bool doL1 = (p >= 1 && p <= T_LEN);
    const bool doFC = (p >= 2);

    // ---- S1: load h caches (h1_{p-1}, h2_{p-2}) ----
    {
      const float4* s1 = (const float4*)(h1g + ((p - 1) & 1) * 32768 + group * 4096);
      const float4* s2 = (const float4*)(h2g + (p & 1) * 32768 + group * 4096);
      float4* d1 = (float4*)h1c;
      float4* d2 = (float4*)h2c;
      for (int i = tid; i < 1024; i += NTH) { d1[i] = s1[i]; d2[i] = s2[i]; }
    }
    __syncthreads();

    // ---- S2: partial dot products ----
    if (doL0) {
      const float* wr = whh0_s + row * WST;
      float a0[4] = {0.f, 0.f, 0.f, 0.f};
      const int k0 = kq * 64;
      #pragma unroll 4
      for (int k = k0; k < k0 + 64; k += 4) {
        float4 w = *(const float4*)(wr + k);
        #pragma unroll
        for (int bb = 0; bb < 4; ++bb) {
          float4 h = *(const float4*)(h1c + (bq * 4 + bb) * 256 + k);
          a0[bb] = fmaf(w.x, h.x, fmaf(w.y, h.y, fmaf(w.z, h.z, fmaf(w.w, h.w, a0[bb]))));
        }
      }
      #pragma unroll
      for (int bb = 0; bb < 4; ++bb)
        gp0[(kq * 16 + bq * 4 + bb) * GPST + row] = a0[bb];
    }
    if (doL1) {
      const float* wr1 = wih1_s + row * WST;
      const float* wr2 = whh1_s + row * WST;
      float a1[4] = {0.f, 0.f, 0.f, 0.f};
      const int k0 = kq * 64;
      #pragma unroll 2
      for (int k = k0; k < k0 + 64; k += 4) {
        float4 u = *(const float4*)(wr1 + k);
        float4 v = *(const float4*)(wr2 + k);
        #pragma unroll
        for (int bb = 0; bb < 4; ++bb) {
          float4 h = *(const float4*)(h1c + (bq * 4 + bb) * 256 + k);
          float4 g = *(const float4*)(h2c + (bq * 4 + bb) * 256 + k);
          float s = fmaf(u.x, h.x, fmaf(u.y, h.y, fmaf(u.z, h.z, u.w * h.w)));
          s = fmaf(v.x, g.x, fmaf(v.y, g.y, fmaf(v.z, g.z, fmaf(v.w, g.w, s))));
          a1[bb] += s;
        }
      }
      #pragma unroll
      for (int bb = 0; bb < 4; ++bb)
        gp1[(kq * 16 + bq * 4 + bb) * GPST + row] = a1[bb];
    }
    // FC partials for step p-2 (slice 0 only; h2c holds h2_{p-2})
    if (doFC && slice == 0 && tid >= 256) {
      int t3 = tid - 256;
      int fb = t3 >> 4, sub = t3 & 15;
      int cls = sub >> 3, r = sub & 7;
      const float* hv = h2c + fb * 256 + r * 32;
      const float* wv = wfc_s + cls * 256 + r * 32;
      float s = 0.f;
      #pragma unroll
      for (int k = 0; k < 32; ++k) s = fmaf(hv[k], wv[k], s);
      fcp[(fb * 2 + cls) * 8 + r] = s;
    }
    __syncthreads();

    // ---- S3: gate reduce + state update + h/out writes ----
    if (tid < 128) {
      if (doL0) {
        const int b = tid >> 3, hs = tid & 7;
        float xx[4];
        const int yb = (group * BPG + b) * T_LEN;
        #pragma unroll
        for (int kk = 0; kk < 4; ++kk) {
          int ti = p + kk - 3;
          xx[kk] = (ti >= 0) ? y[yb + ti] : -100.0f;
        }
        float g4[4];
        #pragma unroll
        for (int gate = 0; gate < 4; ++gate) {
          int rl = gate * 8 + hs;
          float s = b0_s[rl];
          #pragma unroll
          for (int q = 0; q < 4; ++q) s += gp0[(q * 16 + b) * GPST + rl];
          #pragma unroll
          for (int kk = 0; kk < 4; ++kk) s = fmaf(xx[kk], wih0_s[rl * 4 + kk], s);
          g4[gate] = s;
        }
        c1 = sigm(g4[1]) * c1 + sigm(g4[0]) * tanhf(g4[2]);
        float h1v = sigm(g4[3]) * tanhf(c1);
        h1g[(p & 1) * 32768 + group * 4096 + b * 256 + slice * 8 + hs] = h1v;
      }
    } else if (tid < 256) {
      if (doL1) {
        const int t2 = tid - 128;
        const int b = t2 >> 3, hs = t2 & 7;
        float g4[4];
        #pragma unroll
        for (int gate = 0; gate < 4; ++gate) {
          int rl = gate * 8 + hs;
          float s = b1_s[rl];
          #pragma unroll
          for (int q = 0; q < 4; ++q) s += gp1[(q * 16 + b) * GPST + rl];
          g4[gate] = s;
        }
        c2 = sigm(g4[1]) * c2 + sigm(g4[0]) * tanhf(g4[2]);
        float h2v = sigm(g4[3]) * tanhf(c2);
        h2g[((p - 1) & 1) * 32768 + group * 4096 + b * 256 + slice * 8 + hs] = h2v;
      }
    } else if (tid < 288) {
      if (doFC && slice == 0) {
        const int t3 = tid - 256;
        const int b = t3 >> 1, cls = t3 & 1;
        float s = bfc[cls];
        #pragma unroll
        for (int r = 0; r < 8; ++r) s += fcp[(b * 2 + cls) * 8 + r];
        out[(group * BPG + b) * (T_LEN * 2) + (p - 2) * 2 + cls] = s;
      }
    }

    if (p == T_LEN + 1) break;  // final phase: nothing after, skip barrier

    // ---- group barrier (32 blocks), release/acquire via device-scope fences ----
    __threadfence();
    __syncthreads();
    if (tid == 0) {
      const int target = (p + 1) * NSLC;
      int ticket = atomicAdd(arrive, 1);
      if (ticket == target - 1) {
        __hip_atomic_store(epoch, p + 1, __ATOMIC_RELEASE, __HIP_MEMORY_SCOPE_AGENT);
      } else {
        bool ok = false;
        for (int it = 0; it < (1 << 22); ++it) {
          if (__hip_atomic_load(epoch, __ATOMIC_ACQUIRE, __HIP_MEMORY_SCOPE_AGENT) >= p + 1) {
            ok = true; break;
          }
          if ((it & 63) == 63 &&
              __hip_atomic_load(abortf, __ATOMIC_RELAXED, __HIP_MEMORY_SCOPE_AGENT) != 0)
            break;  // someone aborted; bail (results will be wrong but kernel terminates)
          __builtin_amdgcn_s_sleep(1);
        }
        if (!ok) __hip_atomic_store(abortf, 1, __ATOMIC_RELAXED, __HIP_MEMORY_SCOPE_AGENT);
      }
    }
    __syncthreads();
    __threadfence();  // acquire: invalidate L1 before next phase's h loads
  }
}

extern "C" void kernel_launch(void* const* d_in, const int* in_sizes, int n_in,
                              void* d_out, int out_size, void* d_ws, size_t ws_size,
                              hipStream_t stream) {
  const float* y    = (const float*)d_in[0];
  const float* Wih0 = (const float*)d_in[1];
  const float* Whh0 = (const float*)d_in[2];
  const float* bih0 = (const float*)d_in[3];
  const float* bhh0 = (const float*)d_in[4];
  const float* Wih1 = (const float*)d_in[5];
  const float* Whh1 = (const float*)d_in[6];
  const float* bih1 = (const float*)d_in[7];
  const float* bhh1 = (const float*)d_in[8];
  const float* Wfc  = (const float*)d_in[9];
  const float* bfc  = (const float*)d_in[10];
  float* out = (float*)d_out;
  float* ws  = (float*)d_ws;

  // allow 154368 B of dynamic LDS (idempotent; host-side, not captured as a node)
  (void)hipFuncSetAttribute(reinterpret_cast<const void*>(lstm_persist),
                            hipFuncAttributeMaxDynamicSharedMemorySize, 154368);

  hipLaunchKernelGGL(init_ws_kernel, dim3(64), dim3(256), 0, stream, (int*)d_ws);
  hipLaunchKernelGGL(lstm_persist, dim3(256), dim3(NTH), 154368, stream,
                     y, Wih0, Whh0, bih0, bhh0, Wih1, Whh1, bih1, bhh1,
                     Wfc, bfc, out, ws);
}

// Round 2
// 23597.899 us; speedup vs baseline: 6.7817x; 6.7817x over previous
//
#include <hip/hip_runtime.h>
#include <math.h>

// ---------------- problem constants ----------------
#define T_LEN 2048
#define B_SZ  128
#define H_SZ  256
#define NGRP  8      // batch groups (16 batches each)
#define NSLC  32     // gate slices (blocks per group)
#define BPG   16     // batches per group
#define NTH   512    // threads per block
#define WST   260    // padded LDS row stride (floats)
#define GPST  35     // gate-partial stride (floats)

// ---------------- ws layout (float/int units) ----------------
#define H1G_OFF 0              // 2 * 128 * 256 floats (ping-pong h1)
#define H2G_OFF 65536          // 2 * 128 * 256 floats (ping-pong h2)
#define BAR_OFF 131072         // 8 groups * 64 ints (arrive@0, epoch@16), abort @ 8*64
#define WS_INTS (131072 + 512 + 1)

__device__ __forceinline__ float sigm(float x) { return 1.0f / (1.0f + expf(-x)); }

typedef unsigned long long u64t;

__global__ void init_ws_kernel(int* ws) {
  for (int i = blockIdx.x * blockDim.x + threadIdx.x; i < WS_INTS;
       i += gridDim.x * blockDim.x)
    ws[i] = 0;
}

__launch_bounds__(NTH)
__global__ void lstm_persist(const float* __restrict__ y,
                             const float* __restrict__ Wih0, const float* __restrict__ Whh0,
                             const float* __restrict__ bih0, const float* __restrict__ bhh0,
                             const float* __restrict__ Wih1, const float* __restrict__ Whh1,
                             const float* __restrict__ bih1, const float* __restrict__ bhh1,
                             const float* __restrict__ Wfc, const float* __restrict__ bfc,
                             float* __restrict__ out, float* wsf) {
  extern __shared__ float sm[];
  float* whh0_s = sm;
  float* wih1_s = sm + 8320;
  float* whh1_s = sm + 16640;
  float* h1c    = sm + 24960;   // [16][256]  h1_{p-1}
  float* h2c    = sm + 29056;   // [16][256]  h2_{p-2}
  float* gp0    = sm + 33152;   // [64][GPST] partial gates L0
  float* gp1    = sm + 35392;   // [64][GPST] partial gates L1
  float* wfc_s  = sm + 37632;   // [2][256]
  float* wih0_s = sm + 38144;   // [32][4]
  float* b0_s   = sm + 38272;   // [32]
  float* b1_s   = sm + 38304;   // [32]
  float* fcp    = sm + 38336;   // [16][2][8]

  const int tid   = threadIdx.x;
  const int group = blockIdx.x & 7;
  const int slice = blockIdx.x >> 3;

  float* h1g = wsf + H1G_OFF;
  float* h2g = wsf + H2G_OFF;
  int* bar    = (int*)wsf + BAR_OFF;
  int* arrive = bar + group * 64;
  int* epoch  = bar + group * 64 + 16;
  int* abortf = bar + NGRP * 64;

  // ---- stage persistent weight slice into LDS (once) ----
  for (int i = tid; i < 32 * 256; i += NTH) {
    int rl = i >> 8, k = i & 255;
    int gr = (rl >> 3) * 256 + slice * 8 + (rl & 7);
    whh0_s[rl * WST + k] = Whh0[gr * 256 + k];
    wih1_s[rl * WST + k] = Wih1[gr * 256 + k];
    whh1_s[rl * WST + k] = Whh1[gr * 256 + k];
  }
  if (tid < 128) {
    int rl = tid >> 2, k = tid & 3;
    int gr = (rl >> 3) * 256 + slice * 8 + (rl & 7);
    wih0_s[tid] = Wih0[gr * 4 + k];
  }
  if (tid < 32) {
    int gr = (tid >> 3) * 256 + slice * 8 + (tid & 7);
    b0_s[tid] = bih0[gr] + bhh0[gr];
    b1_s[tid] = bih1[gr] + bhh1[gr];
  }
  for (int i = tid; i < 512; i += NTH) wfc_s[i] = Wfc[i];
  __syncthreads();

  // dot-phase roles
  const int row = tid & 31;         // local gate row
  const int bq  = (tid >> 5) & 3;   // batch quad
  const int kq  = tid >> 7;         // k chunk (64 wide)

  float c1 = 0.f, c2 = 0.f;

  for (int p = 0; p <= T_LEN + 1; ++p) {
    const bool doL0 = (p < T_LEN);
    const bool doL1 = (p >= 1 && p <= T_LEN);
    const bool doFC = (p >= 2);

    // ---- S1: load h caches via IF$-coherent (sc1) relaxed atomic loads ----
    {
      const u64t* s1 = (const u64t*)(h1g + ((p - 1) & 1) * 32768 + group * 4096);
      const u64t* s2 = (const u64t*)(h2g + (p & 1) * 32768 + group * 4096);
      u64t* d1 = (u64t*)h1c;
      u64t* d2 = (u64t*)h2c;
      #pragma unroll
      for (int it = 0; it < 4; ++it) {
        int i = tid + it * NTH;
        u64t a = __hip_atomic_load(s1 + i, __ATOMIC_RELAXED, __HIP_MEMORY_SCOPE_AGENT);
        u64t b = __hip_atomic_load(s2 + i, __ATOMIC_RELAXED, __HIP_MEMORY_SCOPE_AGENT);
        d1[i] = a;
        d2[i] = b;
      }
    }
    __syncthreads();

    // ---- S2: partial dot products ----
    if (doL0) {
      const float* wr = whh0_s + row * WST;
      float a0[4] = {0.f, 0.f, 0.f, 0.f};
      const int k0 = kq * 64;
      #pragma unroll 4
      for (int k = k0; k < k0 + 64; k += 4) {
        float4 w = *(const float4*)(wr + k);
        #pragma unroll
        for (int bb = 0; bb < 4; ++bb) {
          float4 h = *(const float4*)(h1c + (bq * 4 + bb) * 256 + k);
          a0[bb] = fmaf(w.x, h.x, fmaf(w.y, h.y, fmaf(w.z, h.z, fmaf(w.w, h.w, a0[bb]))));
        }
      }
      #pragma unroll
      for (int bb = 0; bb < 4; ++bb)
        gp0[(kq * 16 + bq * 4 + bb) * GPST + row] = a0[bb];
    }
    if (doL1) {
      const float* wr1 = wih1_s + row * WST;
      const float* wr2 = whh1_s + row * WST;
      float a1[4] = {0.f, 0.f, 0.f, 0.f};
      const int k0 = kq * 64;
      #pragma unroll 2
      for (int k = k0; k < k0 + 64; k += 4) {
        float4 u = *(const float4*)(wr1 + k);
        float4 v = *(const float4*)(wr2 + k);
        #pragma unroll
        for (int bb = 0; bb < 4; ++bb) {
          float4 h = *(const float4*)(h1c + (bq * 4 + bb) * 256 + k);
          float4 g = *(const float4*)(h2c + (bq * 4 + bb) * 256 + k);
          float s = fmaf(u.x, h.x, fmaf(u.y, h.y, fmaf(u.z, h.z, u.w * h.w)));
          s = fmaf(v.x, g.x, fmaf(v.y, g.y, fmaf(v.z, g.z, fmaf(v.w, g.w, s))));
          a1[bb] += s;
        }
      }
      #pragma unroll
      for (int bb = 0; bb < 4; ++bb)
        gp1[(kq * 16 + bq * 4 + bb) * GPST + row] = a1[bb];
    }
    if (doFC && slice == 0 && tid >= 256) {
      int t3 = tid - 256;
      int fb = t3 >> 4, sub = t3 & 15;
      int cls = sub >> 3, r = sub & 7;
      const float* hv = h2c + fb * 256 + r * 32;
      const float* wv = wfc_s + cls * 256 + r * 32;
      float s = 0.f;
      #pragma unroll
      for (int k = 0; k < 32; ++k) s = fmaf(hv[k], wv[k], s);
      fcp[(fb * 2 + cls) * 8 + r] = s;
    }
    __syncthreads();

    // ---- S3: gate reduce + state update + h/out writes ----
    if (tid < 128) {
      if (doL0) {
        const int b = tid >> 3, hs = tid & 7;
        float xx[4];
        const int yb = (group * BPG + b) * T_LEN;
        #pragma unroll
        for (int kk = 0; kk < 4; ++kk) {
          int ti = p + kk - 3;
          xx[kk] = (ti >= 0) ? y[yb + ti] : -100.0f;
        }
        float g4[4];
        #pragma unroll
        for (int gate = 0; gate < 4; ++gate) {
          int rl = gate * 8 + hs;
          float s = b0_s[rl];
          #pragma unroll
          for (int q = 0; q < 4; ++q) s += gp0[(q * 16 + b) * GPST + rl];
          #pragma unroll
          for (int kk = 0; kk < 4; ++kk) s = fmaf(xx[kk], wih0_s[rl * 4 + kk], s);
          g4[gate] = s;
        }
        c1 = sigm(g4[1]) * c1 + sigm(g4[0]) * tanhf(g4[2]);
        float h1v = sigm(g4[3]) * tanhf(c1);
        // write-through (sc1) store: visible at IF$ once vmcnt retires
        __hip_atomic_store(&h1g[(p & 1) * 32768 + group * 4096 + b * 256 + slice * 8 + hs],
                           h1v, __ATOMIC_RELAXED, __HIP_MEMORY_SCOPE_AGENT);
      }
    } else if (tid < 256) {
      if (doL1) {
        const int t2 = tid - 128;
        const int b = t2 >> 3, hs = t2 & 7;
        float g4[4];
        #pragma unroll
        for (int gate = 0; gate < 4; ++gate) {
          int rl = gate * 8 + hs;
          float s = b1_s[rl];
          #pragma unroll
          for (int q = 0; q < 4; ++q) s += gp1[(q * 16 + b) * GPST + rl];
          g4[gate] = s;
        }
        c2 = sigm(g4[1]) * c2 + sigm(g4[0]) * tanhf(g4[2]);
        float h2v = sigm(g4[3]) * tanhf(c2);
        __hip_atomic_store(&h2g[((p - 1) & 1) * 32768 + group * 4096 + b * 256 + slice * 8 + hs],
                           h2v, __ATOMIC_RELAXED, __HIP_MEMORY_SCOPE_AGENT);
      }
    } else if (tid < 288) {
      if (doFC && slice == 0) {
        const int t3 = tid - 256;
        const int b = t3 >> 1, cls = t3 & 1;
        float s = bfc[cls];
        #pragma unroll
        for (int r = 0; r < 8; ++r) s += fcp[(b * 2 + cls) * 8 + r];
        out[(group * BPG + b) * (T_LEN * 2) + (p - 2) * 2 + cls] = s;
      }
    }

    if (p == T_LEN + 1) break;

    // ---- group barrier: NO cache-maintenance fences ----
    // h stores above are write-through (sc1); vmcnt(0) = acked at IF$.
    asm volatile("s_waitcnt vmcnt(0)" ::: "memory");
    __syncthreads();
    if (tid == 0) {
      const int target = (p + 1) * NSLC;
      int ticket = atomicAdd(arrive, 1);  // relaxed, device-scope
      if (ticket == target - 1) {
        __hip_atomic_store(epoch, p + 1, __ATOMIC_RELAXED, __HIP_MEMORY_SCOPE_AGENT);
      } else {
        bool ok = false;
        for (int it = 0; it < (1 << 22); ++it) {
          if (__hip_atomic_load(epoch, __ATOMIC_RELAXED, __HIP_MEMORY_SCOPE_AGENT) >= p + 1) {
            ok = true; break;
          }
          if ((it & 63) == 63 &&
              __hip_atomic_load(abortf, __ATOMIC_RELAXED, __HIP_MEMORY_SCOPE_AGENT) != 0)
            break;
          __builtin_amdgcn_s_sleep(1);
        }
        if (!ok) __hip_atomic_store(abortf, 1, __ATOMIC_RELAXED, __HIP_MEMORY_SCOPE_AGENT);
      }
    }
    __syncthreads();
  }
}

extern "C" void kernel_launch(void* const* d_in, const int* in_sizes, int n_in,
                              void* d_out, int out_size, void* d_ws, size_t ws_size,
                              hipStream_t stream) {
  const float* y    = (const float*)d_in[0];
  const float* Wih0 = (const float*)d_in[1];
  const float* Whh0 = (const float*)d_in[2];
  const float* bih0 = (const float*)d_in[3];
  const float* bhh0 = (const float*)d_in[4];
  const float* Wih1 = (const float*)d_in[5];
  const float* Whh1 = (const float*)d_in[6];
  const float* bih1 = (const float*)d_in[7];
  const float* bhh1 = (const float*)d_in[8];
  const float* Wfc  = (const float*)d_in[9];
  const float* bfc  = (const float*)d_in[10];
  float* out = (float*)d_out;
  float* ws  = (float*)d_ws;

  (void)hipFuncSetAttribute(reinterpret_cast<const void*>(lstm_persist),
                            hipFuncAttributeMaxDynamicSharedMemorySize, 154368);

  hipLaunchKernelGGL(init_ws_kernel, dim3(64), dim3(256), 0, stream, (int*)d_ws);
  hipLaunchKernelGGL(lstm_persist, dim3(256), dim3(NTH), 154368, stream,
                     y, Wih0, Whh0, bih0, bhh0, Wih1, Whh1, bih1, bhh1,
                     Wfc, bfc, out, ws);
}

// Round 3
// 6621.307 us; speedup vs baseline: 24.1695x; 3.5639x over previous
//
#include <hip/hip_runtime.h>
#include <math.h>

// ---------------- problem constants ----------------
#define T_LEN 2048
#define NGRP  16     // batch groups (8 batches each)
#define NSLC  16     // slices per group (16 hidden units per block per layer)
#define BPG   8      // batches per group
#define NTH   512    // 8 waves: waves 0-3 = L0 tiles, 4-7 = L1 tiles

typedef __attribute__((ext_vector_type(8))) short short8v;  // 8 bf16 = 4 VGPR
typedef __attribute__((ext_vector_type(4))) float f32x4;
typedef unsigned int u32t;
typedef unsigned long long u64t;

// ---------------- ws layout (u32 units) ----------------
#define H1G_OFF 0              // [2][NGRP][BPG][256] packed (hi<<16|lo) bf16 pair
#define H2G_OFF 65536
#define FLG_OFF 131072         // [NGRP][32] flags, one 128B line per group
#define ABT_OFF (131072 + 512)
#define WS_U32  (131072 + 512 + 1)

// ---------------- LDS byte offsets: 4 caches [16 rows][264 bf16] (528B rows) ----
#define L_H1HI 0
#define L_H1LO 8448
#define L_H2HI 16896
#define L_H2LO 25344
#define HROWB  528
// total used: 33792 B; we allocate 131072 dynamic to force 1 block/CU

__device__ __forceinline__ float sigm(float x) { return 1.0f / (1.0f + expf(-x)); }

__device__ __forceinline__ u32t bf_rn(float x) {   // fp32 -> bf16 bits, RNE
  u32t b; __builtin_memcpy(&b, &x, 4);
  return (b + 0x7FFFu + ((b >> 16) & 1u)) >> 16;
}
__device__ __forceinline__ void split_bf(float x, u32t& hi, u32t& lo) {
  hi = bf_rn(x);
  u32t hb = hi << 16; float hf; __builtin_memcpy(&hf, &hb, 4);
  lo = bf_rn(x - hf);
}

__global__ void init_ws_kernel(u32t* ws) {
  for (int i = blockIdx.x * blockDim.x + threadIdx.x; i < WS_U32;
       i += gridDim.x * blockDim.x)
    ws[i] = 0;
}

__launch_bounds__(NTH, 2)
__global__ void lstm_persist(const float* __restrict__ y,
                             const float* __restrict__ Wih0, const float* __restrict__ Whh0,
                             const float* __restrict__ bih0, const float* __restrict__ bhh0,
                             const float* __restrict__ Wih1, const float* __restrict__ Whh1,
                             const float* __restrict__ bih1, const float* __restrict__ bhh1,
                             const float* __restrict__ Wfc, const float* __restrict__ bfc,
                             float* __restrict__ out, u32t* wsu) {
  extern __shared__ char lds[];
  const int tid   = threadIdx.x;
  const int lane  = tid & 63;
  const int wid   = tid >> 6;
  const int group = blockIdx.x & 15;   // blocks of a group stride 16 -> same XCD
  const int slice = blockIdx.x >> 4;

  u32t* flags  = wsu + FLG_OFF + group * 32;
  u32t* abortf = wsu + ABT_OFF;

  // zero upper batch rows (8..15) of all 4 caches (never written again)
  for (int i = tid; i < 1056; i += NTH) {
    ((u32t*)(lds + L_H1HI))[1056 + i] = 0;
    ((u32t*)(lds + L_H1LO))[1056 + i] = 0;
    ((u32t*)(lds + L_H2HI))[1056 + i] = 0;
    ((u32t*)(lds + L_H2LO))[1056 + i] = 0;
  }

  // ---- A-fragment preload (weights -> registers, split hi/lo bf16) ----
  // A layout (16x16x32): lane holds A[m=lane&15][k=(lane>>4)*8 + j], j=0..7
  const int m     = lane & 15;
  const int kq4   = lane >> 4;
  const int gateA = m & 3, hs4A = m >> 2;      // row order m = hs4*4 + gate
  const int hidA  = slice * 16 + (wid & 3) * 4 + hs4A;
  const int growA = gateA * 256 + hidA;

  const bool isL1  = (wid >= 4);
  const bool hasFC = (wid == 0 && slice == 0);
  const float* WA = isL1 ? Wih1 : Whh0;                 // -> ahi/alo[0..7]
  const float* WB = isL1 ? Whh1 : Wfc;                  // -> ahi/alo[8..15]
  const int   rowB  = isL1 ? growA : m;                 // Wfc row = class m
  const bool  bValid = isL1 || (hasFC && m < 2);

  short8v ahi[16], alo[16];
  #pragma unroll
  for (int ks = 0; ks < 8; ++ks) {
    short8v h0, l0, h1, l1;
    #pragma unroll
    for (int j = 0; j < 8; ++j) {
      int k = ks * 32 + kq4 * 8 + j;
      u32t hi, lo;
      split_bf(WA[growA * 256 + k], hi, lo);
      h0[j] = (short)hi; l0[j] = (short)lo;
      float vb = bValid ? WB[rowB * 256 + k] : 0.f;
      split_bf(vb, hi, lo);
      h1[j] = (short)hi; l1[j] = (short)lo;
    }
    ahi[ks] = h0;     alo[ks] = l0;
    ahi[8 + ks] = h1; alo[8 + ks] = l1;
  }

  // ---- per-lane C-layout preloads (C: col=lane&15, row=(lane>>4)*4+reg) ----
  const int batch = lane & 15;                 // valid if < BPG
  const int hidC  = slice * 16 + (wid & 3) * 4 + (lane >> 4);
  float bias4[4], wx[16];
  #pragma unroll
  for (int r = 0; r < 4; ++r) {
    int row = r * 256 + hidC;
    bias4[r] = isL1 ? (bih1[row] + bhh1[row]) : (bih0[row] + bhh0[row]);
    #pragma unroll
    for (int kk = 0; kk < 4; ++kk)
      wx[r * 4 + kk] = isL1 ? 0.f : Wih0[row * 4 + kk];
  }
  float bfc0 = 0.f, bfc1 = 0.f;
  if (hasFC) { bfc0 = bfc[0]; bfc1 = bfc[1]; }
  const float* yb = y + (group * BPG + (batch & 7)) * T_LEN;

  float cst = 0.f;   // lane-local cell state (c1 for L0 waves, c2 for L1 waves)

  __syncthreads();

  for (int p = 0; p <= T_LEN + 1; ++p) {
    const bool doL0 = !isL1 && (p < T_LEN);
    const bool doL1 = isL1 && (p >= 1 && p <= T_LEN);
    const bool doFC = hasFC && (p >= 2);

    // ---- S1: fetch packed h from IF$, unpack into hi/lo LDS caches ----
    {
      const u64t* s1 = (const u64t*)(wsu + H1G_OFF + ((p & 1) ^ 1) * 32768 + group * 2048);
      const u64t* s2 = (const u64t*)(wsu + H2G_OFF + (p & 1) * 32768 + group * 2048);
      #pragma unroll
      for (int it = 0; it < 2; ++it) {
        int idx = tid + it * NTH;
        int ba  = (idx >> 7) * HROWB + (idx & 127) * 4;
        u64t v1 = __hip_atomic_load(s1 + idx, __ATOMIC_RELAXED, __HIP_MEMORY_SCOPE_AGENT);
        u64t v2 = __hip_atomic_load(s2 + idx, __ATOMIC_RELAXED, __HIP_MEMORY_SCOPE_AGENT);
        u32t a0 = (u32t)v1, a1 = (u32t)(v1 >> 32);
        *(u32t*)(lds + L_H1HI + ba) = (a0 >> 16) | (a1 & 0xFFFF0000u);
        *(u32t*)(lds + L_H1LO + ba) = (a0 & 0xFFFFu) | (a1 << 16);
        u32t b0 = (u32t)v2, b1 = (u32t)(v2 >> 32);
        *(u32t*)(lds + L_H2HI + ba) = (b0 >> 16) | (b1 & 0xFFFF0000u);
        *(u32t*)(lds + L_H2LO + ba) = (b0 & 0xFFFFu) | (b1 << 16);
      }
    }
    __syncthreads();

    // ---- MFMA: gates = W_split x h_split (3-term hi/lo -> ~fp32 accuracy) ----
    // B layout: lane reads h[n=lane&15][k=(lane>>4)*8 + j] = 16 contiguous bytes
    f32x4 acc = {0.f, 0.f, 0.f, 0.f}, accF = {0.f, 0.f, 0.f, 0.f};
    const int bfoff = (lane & 15) * HROWB + (lane >> 4) * 16;
    if (doL0) {
      #pragma unroll
      for (int ks = 0; ks < 8; ++ks) {
        short8v bh = *(const short8v*)(lds + L_H1HI + bfoff + ks * 64);
        short8v bl = *(const short8v*)(lds + L_H1LO + bfoff + ks * 64);
        acc = __builtin_amdgcn_mfma_f32_16x16x32_bf16(ahi[ks], bh, acc, 0, 0, 0);
        acc = __builtin_amdgcn_mfma_f32_16x16x32_bf16(ahi[ks], bl, acc, 0, 0, 0);
        acc = __builtin_amdgcn_mfma_f32_16x16x32_bf16(alo[ks], bh, acc, 0, 0, 0);
      }
    }
    if (doL1) {
      #pragma unroll
      for (int ks = 0; ks < 8; ++ks) {
        short8v b1h = *(const short8v*)(lds + L_H1HI + bfoff + ks * 64);
        short8v b1l = *(const short8v*)(lds + L_H1LO + bfoff + ks * 64);
        short8v b2h = *(const short8v*)(lds + L_H2HI + bfoff + ks * 64);
        short8v b2l = *(const short8v*)(lds + L_H2LO + bfoff + ks * 64);
        acc = __builtin_amdgcn_mfma_f32_16x16x32_bf16(ahi[ks], b1h, acc, 0, 0, 0);
        acc = __builtin_amdgcn_mfma_f32_16x16x32_bf16(ahi[ks], b1l, acc, 0, 0, 0);
        acc = __builtin_amdgcn_mfma_f32_16x16x32_bf16(alo[ks], b1h, acc, 0, 0, 0);
        acc = __builtin_amdgcn_mfma_f32_16x16x32_bf16(ahi[8 + ks], b2h, acc, 0, 0, 0);
        acc = __builtin_amdgcn_mfma_f32_16x16x32_bf16(ahi[8 + ks], b2l, acc, 0, 0, 0);
        acc = __builtin_amdgcn_mfma_f32_16x16x32_bf16(alo[8 + ks], b2h, acc, 0, 0, 0);
      }
    }
    if (doFC) {
      #pragma unroll
      for (int ks = 0; ks < 8; ++ks) {
        short8v b2h = *(const short8v*)(lds + L_H2HI + bfoff + ks * 64);
        short8v b2l = *(const short8v*)(lds + L_H2LO + bfoff + ks * 64);
        accF = __builtin_amdgcn_mfma_f32_16x16x32_bf16(ahi[8 + ks], b2h, accF, 0, 0, 0);
        accF = __builtin_amdgcn_mfma_f32_16x16x32_bf16(ahi[8 + ks], b2l, accF, 0, 0, 0);
        accF = __builtin_amdgcn_mfma_f32_16x16x32_bf16(alo[8 + ks], b2h, accF, 0, 0, 0);
      }
    }

    // ---- nonlinearity + state update + h write-through ----
    if (doL0 || doL1) {
      float g[4];
      #pragma unroll
      for (int r = 0; r < 4; ++r) g[r] = acc[r] + bias4[r];
      if (doL0) {
        #pragma unroll
        for (int kk = 0; kk < 4; ++kk) {
          int ti = p + kk - 3;
          float xv = (ti >= 0) ? yb[ti] : -100.0f;
          #pragma unroll
          for (int r = 0; r < 4; ++r) g[r] = fmaf(wx[r * 4 + kk], xv, g[r]);
        }
      }
      cst = sigm(g[1]) * cst + sigm(g[0]) * tanhf(g[2]);
      float hv = sigm(g[3]) * tanhf(cst);
      u32t hi, lo; split_bf(hv, hi, lo);
      u32t pk = (hi << 16) | lo;
      if (batch < BPG) {
        u32t* dst = isL1
            ? (wsu + H2G_OFF + ((p & 1) ^ 1) * 32768 + group * 2048 + batch * 256 + hidC)
            : (wsu + H1G_OFF + (p & 1) * 32768 + group * 2048 + batch * 256 + hidC);
        __hip_atomic_store(dst, pk, __ATOMIC_RELAXED, __HIP_MEMORY_SCOPE_AGENT);
      }
    }
    if (doFC && lane < 8) {
      out[(group * BPG + lane) * (T_LEN * 2) + (p - 2) * 2 + 0] = accF[0] + bfc0;
      out[(group * BPG + lane) * (T_LEN * 2) + (p - 2) * 2 + 1] = accF[1] + bfc1;
    }

    if (p == T_LEN + 1) break;

    // ---- flag barrier: no RMW, no cache maintenance ----
    asm volatile("s_waitcnt vmcnt(0)" ::: "memory");  // h stores acked at IF$
    __syncthreads();
    if (tid == 0)
      __hip_atomic_store(&flags[slice], (u32t)(p + 1),
                         __ATOMIC_RELAXED, __HIP_MEMORY_SCOPE_AGENT);
    {
      const u32t tgt = (u32t)(p + 1);
      bool ok = false;
      for (int it = 0; it < (1 << 20); ++it) {
        u32t f = __hip_atomic_load(&flags[lane & 15],
                                   __ATOMIC_RELAXED, __HIP_MEMORY_SCOPE_AGENT);
        if (__all(f >= tgt)) { ok = true; break; }
        if ((it & 63) == 63 &&
            __hip_atomic_load(abortf, __ATOMIC_RELAXED, __HIP_MEMORY_SCOPE_AGENT) != 0)
          break;
        __builtin_amdgcn_s_sleep(1);
      }
      if (!ok) __hip_atomic_store(abortf, 1, __ATOMIC_RELAXED, __HIP_MEMORY_SCOPE_AGENT);
    }
  }
}

extern "C" void kernel_launch(void* const* d_in, const int* in_sizes, int n_in,
                              void* d_out, int out_size, void* d_ws, size_t ws_size,
                              hipStream_t stream) {
  const float* y    = (const float*)d_in[0];
  const float* Wih0 = (const float*)d_in[1];
  const float* Whh0 = (const float*)d_in[2];
  const float* bih0 = (const float*)d_in[3];
  const float* bhh0 = (const float*)d_in[4];
  const float* Wih1 = (const float*)d_in[5];
  const float* Whh1 = (const float*)d_in[6];
  const float* bih1 = (const float*)d_in[7];
  const float* bhh1 = (const float*)d_in[8];
  const float* Wfc  = (const float*)d_in[9];
  const float* bfc  = (const float*)d_in[10];
  float* out = (float*)d_out;
  u32t* ws   = (u32t*)d_ws;

  (void)hipFuncSetAttribute(reinterpret_cast<const void*>(lstm_persist),
                            hipFuncAttributeMaxDynamicSharedMemorySize, 131072);

  hipLaunchKernelGGL(init_ws_kernel, dim3(64), dim3(256), 0, stream, ws);
  hipLaunchKernelGGL(lstm_persist, dim3(256), dim3(NTH), 131072, stream,
                     y, Wih0, Whh0, bih0, bhh0, Wih1, Whh1, bih1, bhh1,
                     Wfc, bfc, out, ws);
}